// Round 1
// 403.932 us; speedup vs baseline: 1.0011x; 1.0011x over previous
//
#include <hip/hip_runtime.h>

#define NPTS 131072
#define NCEN 128
#define PFROWS 14   // rgbs rows prefetched to LDS via global_load_lds (57 KB)
#define RROWS  8    // rgbs rows prefetched to registers (rows PFROWS..PFROWS+RROWS-1)

// Mahalanobis quadratic form, numpy-order (mul then add, explicit _rn ops: no
// fma contraction). Called twice per (point,center); inputs come from the same
// LDS copy both times -> bit-identical results, so pass-2 recompute reproduces
// pass-1 selection exactly.
__device__ __forceinline__ float qeval(const float* C,
                                       float px, float py, float pz) {
    float dx = __fsub_rn(px, C[9]);
    float dy = __fsub_rn(py, C[10]);
    float dz = __fsub_rn(pz, C[11]);
    float t0 = __fadd_rn(__fadd_rn(__fmul_rn(dx, C[0]), __fmul_rn(dy, C[3])), __fmul_rn(dz, C[6]));
    float t1 = __fadd_rn(__fadd_rn(__fmul_rn(dx, C[1]), __fmul_rn(dy, C[4])), __fmul_rn(dz, C[7]));
    float t2 = __fadd_rn(__fadd_rn(__fmul_rn(dx, C[2]), __fmul_rn(dy, C[5])), __fmul_rn(dz, C[8]));
    return __fadd_rn(__fadd_rn(__fmul_rn(t0, dx), __fmul_rn(t1, dy)), __fmul_rn(t2, dz));
}

// ---------- kernel 0: zero the pen accumulator (ws is poisoned each iter) ----------
__global__ void k_zero(float* __restrict__ ws) {
    if (threadIdx.x == 0) ws[0] = 0.f;
}

// ---------- kernel 1: everything fused ----------
// R7 changes (all bit-exact vs R6's 403 µs kernel):
//  * inv_cov table computed per-block in LDS (tid<128), k_precompute dropped.
//  * top-16 insert: top[k] = min(top[k], max(q, top[k-1])) with invariant
//    top[k-1] <= top[k] is EXACTLY v_med3_f32(q, top[k-1], top[k]) -> 1 op/slot.
//  * pass-1 (~10 us of pure VALU, memory otherwise idle: single residency
//    generation, 512 blocks = 256 CU x 2) now overlaps the rgbs stream:
//    rows 0..13 are issued to LDS via global_load_lds and rows 14..21 to
//    registers BEFORE the table barrier. Ordering discipline:
//      - wxyz/dists/centers/radii/rots loads are issued FIRST so the
//        compiler's wait for them is a counted vmcnt (in-order retire), not a
//        drain of the 22 prefetch loads behind them;
//      - the table handoff uses raw s_barrier + explicit lgkmcnt(0):
//        __syncthreads() would emit s_waitcnt vmcnt(0) and serialize the
//        prefetch in front of pass-1;
//      - each wave's global_load_lds lands in its own 64-lane LDS segment
//        (wave-uniform base &srgb[r][tid&192] + lane*16), and each lane reads
//        back only its own slot -> no barrier needed before consumption,
//        just vmcnt(0) after pass-1 (long since retired).
// Selection/mask semantics unchanged: qcut = 16th-smallest q; blend mask
// (q <= qcut) && (w >= 0.01); pen guard q <= 13 exact (w(13)=0.0075 < 0.01).
__global__ __launch_bounds__(256, 2) void k_main(
        const float* __restrict__ wxyz,
        const float* __restrict__ centers,
        const float* __restrict__ radii,
        const float* __restrict__ rots,
        const float* __restrict__ dists,
        const float4* __restrict__ rgbs,
        float4* __restrict__ outv,
        float* __restrict__ pen_accum) {
    __shared__ float sws[NCEN * 12];          // 6144 B
    __shared__ float4 srgb[PFROWS][256];      // 57344 B  (total 63488 <= 64K static)

    int tid = threadIdx.x;
    int p = blockIdx.x * 256 + tid;

    // ---- (a) small loads first: their vmcnt waits stay counted, not drains ----
    float px = wxyz[3 * p + 0];
    float py = wxyz[3 * p + 1];
    float pz = wxyz[3 * p + 2];
    float dist = dists[p];

    float c0 = 0.f, c1 = 0.f, c2 = 0.f;
    float rd0 = 0.f, rd1 = 0.f, rd2 = 0.f;
    float a0 = 0.f, a1 = 0.f, a2 = 0.f;
    if (tid < NCEN) {                         // waves 0,1 fully active: no divergence
        c0 = centers[3 * tid + 0];
        c1 = centers[3 * tid + 1];
        c2 = centers[3 * tid + 2];
        rd0 = radii[3 * tid + 0];
        rd1 = radii[3 * tid + 1];
        rd2 = radii[3 * tid + 2];
        a0 = rots[3 * tid + 0];
        a1 = rots[3 * tid + 1];
        a2 = rots[3 * tid + 2];
    }
    asm volatile("" ::: "memory");            // pin: small loads issue before prefetch

    // ---- (b) issue the stream prefetch: 14 rows -> LDS, 8 rows -> registers ----
    typedef __attribute__((address_space(1))) const void GPTR;
    typedef __attribute__((address_space(3))) void LPTR;
    const float4* gsrc = rgbs + p;
#pragma unroll
    for (int r = 0; r < PFROWS; ++r) {
        __builtin_amdgcn_global_load_lds(
            (GPTR*)(gsrc + (size_t)r * NPTS),
            (LPTR*)(&srgb[r][tid & 192]),     // wave-uniform base; HW adds lane*16
            16, 0, 0);
    }
    float4 rpre[RROWS];
#pragma unroll
    for (int r = 0; r < RROWS; ++r)
        rpre[r] = gsrc[(size_t)(PFROWS + r) * NPTS];

    // ---- (c) per-block inv_cov table (identical math to old k_precompute) ----
    if (tid < NCEN) {
        float d0 = 1.0f / (fabsf(rd0) + 1e-8f);
        float d1 = 1.0f / (fabsf(rd1) + 1e-8f);
        float d2 = 1.0f / (fabsf(rd2) + 1e-8f);
        float cx = cosf(a0), cy = cosf(a1), cz = cosf(a2);
        float sx = sinf(a0), sy = sinf(a1), sz = sinf(a2);
        float R[9];
        R[0] = __fmul_rn(cz, cy);
        R[1] = __fsub_rn(__fmul_rn(__fmul_rn(cz, sy), sx), __fmul_rn(sz, cx));
        R[2] = __fadd_rn(__fmul_rn(__fmul_rn(cz, sy), cx), __fmul_rn(sz, sx));
        R[3] = __fmul_rn(sz, cy);
        R[4] = __fadd_rn(__fmul_rn(__fmul_rn(sz, sy), sx), __fmul_rn(cz, cx));
        R[5] = __fsub_rn(__fmul_rn(__fmul_rn(sz, sy), cx), __fmul_rn(cz, sx));
        R[6] = -sy;
        R[7] = __fmul_rn(cy, sx);
        R[8] = __fmul_rn(cy, cx);
        float T[9];
        T[0] = __fmul_rn(R[0], d0); T[1] = __fmul_rn(R[1], d1); T[2] = __fmul_rn(R[2], d2);
        T[3] = __fmul_rn(R[3], d0); T[4] = __fmul_rn(R[4], d1); T[5] = __fmul_rn(R[5], d2);
        T[6] = __fmul_rn(R[6], d0); T[7] = __fmul_rn(R[7], d1); T[8] = __fmul_rn(R[8], d2);
        float* W = &sws[tid * 12];
#pragma unroll
        for (int a = 0; a < 3; ++a)
#pragma unroll
            for (int c = 0; c < 3; ++c)
                W[3 * a + c] = __fadd_rn(__fadd_rn(__fmul_rn(T[3 * a + 0], R[3 * c + 0]),
                                                   __fmul_rn(T[3 * a + 1], R[3 * c + 1])),
                                         __fmul_rn(T[3 * a + 2], R[3 * c + 2]));
        W[9] = c0; W[10] = c1; W[11] = c2;
    }
    // raw barrier: order ds_writes only; do NOT drain vmcnt (prefetch in flight)
    asm volatile("s_waitcnt lgkmcnt(0)" ::: "memory");
    __builtin_amdgcn_s_barrier();

    // ---- pass 1: q over all 128 centers; pen (guarded, exact); top-16 ----
    float top[16];             // 16 smallest q, ascending
#pragma unroll
    for (int i = 0; i < 16; ++i) top[i] = 3.0e38f;
    float pen = 0.f;

    for (int n = 0; n < NCEN; ++n) {
        float q = qeval(&sws[n * 12], px, py, pz);
        if (q <= 13.0f) {
            float wv = __fmul_rn(5.0f, expf(__fmul_rn(-0.5f, q)));
            pen = __fadd_rn(pen, fmaxf(__fsub_rn(wv, 0.01f), 0.f));
        }
        // min(top[k], max(q, top[k-1])) == med3 given top[k-1] <= top[k]:
        // bit-identical selection, one v_med3_f32 per slot instead of two ops.
#pragma unroll
        for (int k = 15; k >= 1; --k)
            top[k] = __builtin_amdgcn_fmed3f(q, top[k - 1], top[k]);
        top[0] = fminf(top[0], q);
    }
    float qcut = top[15];

    // prefetch long since retired (pass-1 ~10us >> HBM latency); cheap drain
    asm volatile("s_waitcnt vmcnt(0)" ::: "memory");

    // ---- pass 2: rows 0..13 from LDS, 14..21 from registers, rest streamed ----
    float wsum = 0.f, s0 = 0.f, s1 = 0.f, s2 = 0.f, s3 = 0.f;
#define ACCUM(nn, rv) do {                                                        \
        float q = qeval(&sws[(nn) * 12], px, py, pz);                             \
        float wv = __fmul_rn(5.0f, expf(__fmul_rn(-0.5f, q)));                    \
        float mw = ((q <= qcut) && (wv >= 0.01f)) ? wv : 0.0f;                    \
        float al = __fsub_rn(1.0f, expf(-__fmul_rn(fmaxf((rv).w, 0.f), dist)));   \
        wsum += mw;                                                               \
        s0 = __fmaf_rn(mw, (rv).x, s0);                                           \
        s1 = __fmaf_rn(mw, (rv).y, s1);                                           \
        s2 = __fmaf_rn(mw, (rv).z, s2);                                           \
        s3 = __fmaf_rn(mw, al, s3);                                               \
    } while (0)

#pragma unroll
    for (int n = 0; n < PFROWS; ++n) {
        float4 rv = srgb[n][tid];
        ACCUM(n, rv);
    }
#pragma unroll
    for (int n = 0; n < RROWS; ++n) {
        ACCUM(PFROWS + n, rpre[n]);
    }
#pragma unroll 8
    for (int n = PFROWS + RROWS; n < NCEN; ++n) {
        float4 rv = rgbs[(size_t)n * NPTS + p];
        ACCUM(n, rv);
    }
#undef ACCUM

    float inv = 1.0f / (wsum + 1e-7f);
    float4 o;
    o.x = s0 * inv; o.y = s1 * inv; o.z = s2 * inv; o.w = s3 * inv;
    outv[p] = o;               // 16B/lane, fully coalesced

    // penalty reduction: wave shuffle, one atomic per wave
    float v = pen;
#pragma unroll
    for (int off = 32; off > 0; off >>= 1) v += __shfl_down(v, off);
    if ((tid & 63) == 0) atomicAdd(pen_accum, v);
}

// ---------- kernel 2: finalize scalar penalty (+ bbox, exactly 0 for these inputs) ----------
__global__ void k_finalize(const float* __restrict__ centers,
                           const float* __restrict__ ws,
                           float* __restrict__ out) {
    int t = threadIdx.x;       // 64 threads
    float bb = 0.f;
    for (int n = t; n < NCEN; n += 64) {
        float c0 = centers[3 * n + 0];
        float c1 = centers[3 * n + 1];
        float c2 = centers[3 * n + 2];
        bb += fmaxf(c0 - 0.5f, 0.f) + fmaxf(-0.5f - c0, 0.f)
            + fmaxf(c1 - 0.5f, 0.f) + fmaxf(-0.5f - c1, 0.f)
            + fmaxf(c2 - 0.5f, 0.f) + fmaxf(-0.5f - c2, 0.f);
    }
#pragma unroll
    for (int off = 32; off > 0; off >>= 1) bb += __shfl_down(bb, off);
    if (t == 0) {
        float m = ws[0] / (float)NPTS;       // mean over points
        out[NPTS * 4] = __fadd_rn(__fmul_rn(0.001f, m), bb);
    }
}

extern "C" void kernel_launch(void* const* d_in, const int* in_sizes, int n_in,
                              void* d_out, int out_size, void* d_ws, size_t ws_size,
                              hipStream_t stream) {
    const float*  wxyz  = (const float*)d_in[0];
    const float*  cen   = (const float*)d_in[1];
    const float*  rad   = (const float*)d_in[2];
    const float*  rot   = (const float*)d_in[3];
    const float4* rgbs  = (const float4*)d_in[4];
    const float*  dists = (const float*)d_in[5];
    float* ws = (float*)d_ws;

    hipLaunchKernelGGL(k_zero, dim3(1), dim3(64), 0, stream, ws);
    hipLaunchKernelGGL(k_main, dim3(NPTS / 256), dim3(256), 0, stream,
                       wxyz, cen, rad, rot, dists, rgbs, (float4*)d_out, ws);
    hipLaunchKernelGGL(k_finalize, dim3(1), dim3(64), 0, stream, cen, ws, (float*)d_out);
}

// Round 2
// 383.531 us; speedup vs baseline: 1.0543x; 1.0532x over previous
//
#include <hip/hip_runtime.h>

#define NPTS 131072
#define NCEN 128
#define RROWS 24   // rgbs rows prefetched to registers (96 VGPRs), hidden under pass-1

// Mahalanobis quadratic form, numpy-order (mul then add, explicit _rn ops: no
// fma contraction). Table stored column-major as 3 float4 per center:
//   v0 = (W[0],W[3],W[6], cx)  v1 = (W[1],W[4],W[7], cy)  v2 = (W[2],W[5],W[8], cz)
// -> exactly 3 ds_read_b128 per eval. Arithmetic order identical to the
// previous scalar version (bit-identical results), so pass-2 recompute
// reproduces pass-1 selection exactly.
__device__ __forceinline__ float qeval4(float4 v0, float4 v1, float4 v2,
                                        float px, float py, float pz) {
    float dx = __fsub_rn(px, v0.w);
    float dy = __fsub_rn(py, v1.w);
    float dz = __fsub_rn(pz, v2.w);
    float t0 = __fadd_rn(__fadd_rn(__fmul_rn(dx, v0.x), __fmul_rn(dy, v0.y)), __fmul_rn(dz, v0.z));
    float t1 = __fadd_rn(__fadd_rn(__fmul_rn(dx, v1.x), __fmul_rn(dy, v1.y)), __fmul_rn(dz, v1.z));
    float t2 = __fadd_rn(__fadd_rn(__fmul_rn(dx, v2.x), __fmul_rn(dy, v2.y)), __fmul_rn(dz, v2.z));
    return __fadd_rn(__fadd_rn(__fmul_rn(t0, dx), __fmul_rn(t1, dy)), __fmul_rn(t2, dz));
}

// ---------- kernel 0: zero the pen accumulator (ws is poisoned each iter) ----------
__global__ void k_zero(float* __restrict__ ws) {
    if (threadIdx.x == 0) ws[0] = 0.f;
}

// ---------- kernel 1: everything fused ----------
// R8 post-mortem of R7's null: global_load_lds WRITES LDS, and pass-1's first
// ds_read of the table cannot be proven disjoint -> the compiler drains
// vmcnt(0) before pass-1, serializing the whole prefetch (timeline identical
// to no-prefetch). Fix: prefetch to REGISTERS only. Grid = 512 blocks =
// 2 blocks/CU (grid-limited, 8 waves/CU) so VGPR budget under
// __launch_bounds__(256,2) is ~256; we use ~96 for 24 float4 rows.
// Order discipline:
//   1. small loads (wxyz/dists + table inputs)      -- counted vmcnt waits
//   2. table build + ds_write (column-major float4)
//   3. lgkmcnt(0) + raw s_barrier                   -- no vmem pending here
//   4. issue 24 global_load_dwordx4 -> rpre[]       -- in flight during pass-1
//   5. pass-1 (VALU + ds_read only; lgkmcnt-domain, no vmcnt interaction)
//   6. pass-2: rpre rows first, stream rows 24..127 (unroll 8)
// Selection semantics unchanged: qcut = 16th-smallest q via med3 ladder;
// blend mask (q <= qcut) && (w >= 0.01); pen guard q <= 13 exact
// (w(13)=0.0075 < 0.01). Masked rows contribute exact +0.0 to all sums.
__global__ __launch_bounds__(256, 2) void k_main(
        const float* __restrict__ wxyz,
        const float* __restrict__ centers,
        const float* __restrict__ radii,
        const float* __restrict__ rots,
        const float* __restrict__ dists,
        const float4* __restrict__ rgbs,
        float4* __restrict__ outv,
        float* __restrict__ pen_accum) {
    __shared__ float4 sws4[NCEN * 3];         // 6144 B

    int tid = threadIdx.x;
    int p = blockIdx.x * 256 + tid;

    // ---- (1) small loads first ----
    float px = wxyz[3 * p + 0];
    float py = wxyz[3 * p + 1];
    float pz = wxyz[3 * p + 2];
    float dist = dists[p];

    // ---- (2) per-block inv_cov table (identical math to before) ----
    if (tid < NCEN) {                         // waves 0,1 fully active
        float c0 = centers[3 * tid + 0];
        float c1 = centers[3 * tid + 1];
        float c2 = centers[3 * tid + 2];
        float d0 = 1.0f / (fabsf(radii[3 * tid + 0]) + 1e-8f);
        float d1 = 1.0f / (fabsf(radii[3 * tid + 1]) + 1e-8f);
        float d2 = 1.0f / (fabsf(radii[3 * tid + 2]) + 1e-8f);
        float a0 = rots[3 * tid + 0];
        float a1 = rots[3 * tid + 1];
        float a2 = rots[3 * tid + 2];
        float cx = cosf(a0), cy = cosf(a1), cz = cosf(a2);
        float sx = sinf(a0), sy = sinf(a1), sz = sinf(a2);
        float R[9];
        R[0] = __fmul_rn(cz, cy);
        R[1] = __fsub_rn(__fmul_rn(__fmul_rn(cz, sy), sx), __fmul_rn(sz, cx));
        R[2] = __fadd_rn(__fmul_rn(__fmul_rn(cz, sy), cx), __fmul_rn(sz, sx));
        R[3] = __fmul_rn(sz, cy);
        R[4] = __fadd_rn(__fmul_rn(__fmul_rn(sz, sy), sx), __fmul_rn(cz, cx));
        R[5] = __fsub_rn(__fmul_rn(__fmul_rn(sz, sy), cx), __fmul_rn(cz, sx));
        R[6] = -sy;
        R[7] = __fmul_rn(cy, sx);
        R[8] = __fmul_rn(cy, cx);
        float T[9];
        T[0] = __fmul_rn(R[0], d0); T[1] = __fmul_rn(R[1], d1); T[2] = __fmul_rn(R[2], d2);
        T[3] = __fmul_rn(R[3], d0); T[4] = __fmul_rn(R[4], d1); T[5] = __fmul_rn(R[5], d2);
        T[6] = __fmul_rn(R[6], d0); T[7] = __fmul_rn(R[7], d1); T[8] = __fmul_rn(R[8], d2);
        float W[9];
#pragma unroll
        for (int a = 0; a < 3; ++a)
#pragma unroll
            for (int c = 0; c < 3; ++c)
                W[3 * a + c] = __fadd_rn(__fadd_rn(__fmul_rn(T[3 * a + 0], R[3 * c + 0]),
                                                   __fmul_rn(T[3 * a + 1], R[3 * c + 1])),
                                         __fmul_rn(T[3 * a + 2], R[3 * c + 2]));
        // column-major store: v_c = (W[0*3+c], W[1*3+c], W[2*3+c], center[c])
        sws4[tid * 3 + 0] = make_float4(W[0], W[3], W[6], c0);
        sws4[tid * 3 + 1] = make_float4(W[1], W[4], W[7], c1);
        sws4[tid * 3 + 2] = make_float4(W[2], W[5], W[8], c2);
    }
    // ---- (3) raw barrier: drain LDS writes only; NO vmem pending here ----
    asm volatile("s_waitcnt lgkmcnt(0)" ::: "memory");
    __builtin_amdgcn_s_barrier();

    // ---- (4) register prefetch: 24 rows in flight across pass-1 ----
    const float4* gsrc = rgbs + p;
    float4 rpre[RROWS];
#pragma unroll
    for (int r = 0; r < RROWS; ++r)
        rpre[r] = gsrc[(size_t)r * NPTS];

    // ---- (5) pass 1: q over all 128 centers; pen (guarded, exact); top-16 ----
    float top[16];             // 16 smallest q, ascending
#pragma unroll
    for (int i = 0; i < 16; ++i) top[i] = 3.0e38f;
    float pen = 0.f;

    for (int n = 0; n < NCEN; ++n) {
        float4 v0 = sws4[n * 3 + 0];
        float4 v1 = sws4[n * 3 + 1];
        float4 v2 = sws4[n * 3 + 2];
        float q = qeval4(v0, v1, v2, px, py, pz);
        if (q <= 13.0f) {
            float wv = __fmul_rn(5.0f, expf(__fmul_rn(-0.5f, q)));
            pen = __fadd_rn(pen, fmaxf(__fsub_rn(wv, 0.01f), 0.f));
        }
        // min(top[k], max(q, top[k-1])) == med3 given top[k-1] <= top[k]:
        // bit-identical selection, one v_med3_f32 per slot.
#pragma unroll
        for (int k = 15; k >= 1; --k)
            top[k] = __builtin_amdgcn_fmed3f(q, top[k - 1], top[k]);
        top[0] = fminf(top[0], q);
    }
    float qcut = top[15];

    // ---- (6) pass 2: rpre rows 0..23, then stream rows 24..127 ----
    float wsum = 0.f, s0 = 0.f, s1 = 0.f, s2 = 0.f, s3 = 0.f;
#define ACCUM(nn, rv) do {                                                        \
        float4 u0 = sws4[(nn) * 3 + 0];                                           \
        float4 u1 = sws4[(nn) * 3 + 1];                                           \
        float4 u2 = sws4[(nn) * 3 + 2];                                           \
        float q = qeval4(u0, u1, u2, px, py, pz);                                 \
        float wv = __fmul_rn(5.0f, expf(__fmul_rn(-0.5f, q)));                    \
        float mw = ((q <= qcut) && (wv >= 0.01f)) ? wv : 0.0f;                    \
        float al = __fsub_rn(1.0f, expf(-__fmul_rn(fmaxf((rv).w, 0.f), dist)));   \
        wsum += mw;                                                               \
        s0 = __fmaf_rn(mw, (rv).x, s0);                                           \
        s1 = __fmaf_rn(mw, (rv).y, s1);                                           \
        s2 = __fmaf_rn(mw, (rv).z, s2);                                           \
        s3 = __fmaf_rn(mw, al, s3);                                               \
    } while (0)

#pragma unroll
    for (int n = 0; n < RROWS; ++n) {
        ACCUM(n, rpre[n]);
    }
#pragma unroll 8
    for (int n = RROWS; n < NCEN; ++n) {
        float4 rv = rgbs[(size_t)n * NPTS + p];
        ACCUM(n, rv);
    }
#undef ACCUM

    float inv = 1.0f / (wsum + 1e-7f);
    float4 o;
    o.x = s0 * inv; o.y = s1 * inv; o.z = s2 * inv; o.w = s3 * inv;
    outv[p] = o;               // 16B/lane, fully coalesced

    // penalty reduction: wave shuffle, one atomic per wave
    float v = pen;
#pragma unroll
    for (int off = 32; off > 0; off >>= 1) v += __shfl_down(v, off);
    if ((tid & 63) == 0) atomicAdd(pen_accum, v);
}

// ---------- kernel 2: finalize scalar penalty (+ bbox, exactly 0 for these inputs) ----------
__global__ void k_finalize(const float* __restrict__ centers,
                           const float* __restrict__ ws,
                           float* __restrict__ out) {
    int t = threadIdx.x;       // 64 threads
    float bb = 0.f;
    for (int n = t; n < NCEN; n += 64) {
        float c0 = centers[3 * n + 0];
        float c1 = centers[3 * n + 1];
        float c2 = centers[3 * n + 2];
        bb += fmaxf(c0 - 0.5f, 0.f) + fmaxf(-0.5f - c0, 0.f)
            + fmaxf(c1 - 0.5f, 0.f) + fmaxf(-0.5f - c1, 0.f)
            + fmaxf(c2 - 0.5f, 0.f) + fmaxf(-0.5f - c2, 0.f);
    }
#pragma unroll
    for (int off = 32; off > 0; off >>= 1) bb += __shfl_down(bb, off);
    if (t == 0) {
        float m = ws[0] / (float)NPTS;       // mean over points
        out[NPTS * 4] = __fadd_rn(__fmul_rn(0.001f, m), bb);
    }
}

extern "C" void kernel_launch(void* const* d_in, const int* in_sizes, int n_in,
                              void* d_out, int out_size, void* d_ws, size_t ws_size,
                              hipStream_t stream) {
    const float*  wxyz  = (const float*)d_in[0];
    const float*  cen   = (const float*)d_in[1];
    const float*  rad   = (const float*)d_in[2];
    const float*  rot   = (const float*)d_in[3];
    const float4* rgbs  = (const float4*)d_in[4];
    const float*  dists = (const float*)d_in[5];
    float* ws = (float*)d_ws;

    hipLaunchKernelGGL(k_zero, dim3(1), dim3(64), 0, stream, ws);
    hipLaunchKernelGGL(k_main, dim3(NPTS / 256), dim3(256), 0, stream,
                       wxyz, cen, rad, rot, dists, rgbs, (float4*)d_out, ws);
    hipLaunchKernelGGL(k_finalize, dim3(1), dim3(64), 0, stream, cen, ws, (float*)d_out);
}